// Round 9
// baseline (192.202 us; speedup 1.0000x reference)
//
#include <hip/hip_runtime.h>
#include <math.h>

#define B_  2
#define D_  1536
#define L_  2048
#define N_  16
#define NH  8                 // states per half-wave
#define LC  128               // chunk length along L (32 segs x 4 elems)
#define NCHUNK (L_ / LC)      // 16
#define NCH (B_ * D_)         // 3072 channels
#define LOG2E 1.4426950408889634f
#define LN2   0.6931471805599453f

typedef float f4 __attribute__((ext_vector_type(4)));
typedef float f8 __attribute__((ext_vector_type(8)));

__device__ __forceinline__ float exp2f_(float v) { return __builtin_amdgcn_exp2f(v); }
__device__ __forceinline__ float log2f_(float v) { return __builtin_amdgcn_logf(v); }
__device__ __forceinline__ float rcpf_(float v)  { return __builtin_amdgcn_rcpf(v); }

__device__ __forceinline__ float softplus_f(float v) {
    float t = exp2f_(v * LOG2E);                   // e^v
    float r = LN2 * log2f_(1.0f + t);              // ln(1+e^v)
    return (v > 20.0f) ? v : r;
}
__device__ __forceinline__ f8 splat8(float v) { f8 r = {v,v,v,v,v,v,v,v}; return r; }
__device__ __forceinline__ f8 exp2v8(f8 a) {
    f8 r;
    r[0]=exp2f_(a[0]); r[1]=exp2f_(a[1]); r[2]=exp2f_(a[2]); r[3]=exp2f_(a[3]);
    r[4]=exp2f_(a[4]); r[5]=exp2f_(a[5]); r[6]=exp2f_(a[6]); r[7]=exp2f_(a[7]);
    return r;
}
__device__ __forceinline__ float dot8(f8 a, f8 b) {
    float p0 = fmaf(a[0], b[0], a[1]*b[1]);
    float p1 = fmaf(a[2], b[2], a[3]*b[3]);
    float p2 = fmaf(a[4], b[4], a[5]*b[5]);
    float p3 = fmaf(a[6], b[6], a[7]*b[7]);
    return (p0 + p1) + (p2 + p3);
}

#define DPP_WAVE_SHR1   0x138
template<int CTRL, int RMASK>
__device__ __forceinline__ float dpp0(float v) {
    return __int_as_float(__builtin_amdgcn_update_dpp(
        0, __float_as_int(v), CTRL, RMASK, 0xF, true));
}

// Round 9 = round-8's 68us kernel (fused-DPP asm scan, proven) + the
// TRANSCENDENTALS SOFTWARE-PIPELINED ONE CHUNK AHEAD.
//
// Round-8 diagnosis: busy 31us-equiv, stall 37us (54%).  Per body there are
// 48 trans ops (4 softplus-exp + 4 log + 32 deltaA exps + 8 epilogue) at
// quarter rate (~8cy/op trans-pipe) whose consumers sit ~10cy downstream
// (e_j feeds pass-1 immediately): each wave bursts 32 exps then stalls on the
// trans pipe, and all 3 phase-identical waves/SIMD hit the burst together.
// Meanwhile scan+fold+pass2 (~400cy of trans-free VALU/DPP) could hide it.
//
// Fix: compute dt/u/e0..e3 for chunk c+1 in the MIDDLE of body c (between
// scan and fold).  Inputs (dv/xv for c+1) were prefetch-issued at body-c top
// (~400cy load cover); consumers are half-a-body + next-body-top away
// (~400-500cy).  The wave issues the trans block and keeps issuing the
// independent fold/pass2/epilogue while the trans unit drains — within-wave
// overlap, trans latency off the critical path.  Same instruction count,
// same math order (bitwise-identical result).
// Register cost: +36 long-lived (4 u + 32 e) -> ~115-135 VGPR, under the
// 168 cap of __launch_bounds__(64,3).  Spill tripwire: WRITE_SIZE != 24576KB.
__global__ __launch_bounds__(64, 3)
void ssm_scan_kernel(const float* __restrict__ x,
                     const float* __restrict__ delta,
                     const float* __restrict__ A,
                     const float* __restrict__ Bm,
                     const float* __restrict__ Cm,
                     const float* __restrict__ Dv,
                     const float* __restrict__ z,
                     const float* __restrict__ dbias,
                     float* __restrict__ out)
{
    const int lane = threadIdx.x;      // 0..63
    const int s    = lane & 31;
    const int g    = lane >> 5;
    const int ch   = blockIdx.x;       // one channel per wave
    const int b    = ch / D_;
    const int d    = ch - b * D_;

    const float bias = dbias[d];
    const float Dd   = Dv[d];

    const float* Ab = A + d * N_ + NH * g;
    f8 A2v;
    A2v[0]=Ab[0]*LOG2E; A2v[1]=Ab[1]*LOG2E; A2v[2]=Ab[2]*LOG2E; A2v[3]=Ab[3]*LOG2E;
    A2v[4]=Ab[4]*LOG2E; A2v[5]=Ab[5]*LOG2E; A2v[6]=Ab[6]*LOG2E; A2v[7]=Ab[7]*LOG2E;

    const float* Bp = Bm + (size_t)b * (N_ * L_) + (size_t)(NH * g) * L_;
    const float* Cp = Cm + (size_t)b * (N_ * L_) + (size_t)(NH * g) * L_;
    const size_t chbase = (size_t)ch * L_;

    f8 carry = splat8(0.0f);

    // ---- early-consumed operands (delta, x, B) double-buffered 1 chunk ahead ----
    f4 P0_dv = *(const f4*)(delta + chbase + s * 4);
    f4 P0_xv = *(const f4*)(x     + chbase + s * 4);
    f4 P0_B0 = *(const f4*)(Bp + 0 * L_ + s * 4);
    f4 P0_B1 = *(const f4*)(Bp + 1 * L_ + s * 4);
    f4 P0_B2 = *(const f4*)(Bp + 2 * L_ + s * 4);
    f4 P0_B3 = *(const f4*)(Bp + 3 * L_ + s * 4);
    f4 P0_B4 = *(const f4*)(Bp + 4 * L_ + s * 4);
    f4 P0_B5 = *(const f4*)(Bp + 5 * L_ + s * 4);
    f4 P0_B6 = *(const f4*)(Bp + 6 * L_ + s * 4);
    f4 P0_B7 = *(const f4*)(Bp + 7 * L_ + s * 4);
    f4 P1_dv, P1_xv, P1_B0, P1_B1, P1_B2, P1_B3, P1_B4, P1_B5, P1_B6, P1_B7;

    // ---- pipelined trans state: dt/u/e for the CURRENT chunk, computed one
    //      body ahead (double-buffered by name) ----
    f8 E0_e0, E0_e1, E0_e2, E0_e3, E1_e0, E1_e1, E1_e2, E1_e3;
    float E0_u0, E0_u1, E0_u2, E0_u3, E1_u0, E1_u1, E1_u2, E1_u3;

#define MAKE_E(EB, DV, XV) \
    { \
        float dt0 = softplus_f(DV.x + bias); \
        float dt1 = softplus_f(DV.y + bias); \
        float dt2 = softplus_f(DV.z + bias); \
        float dt3 = softplus_f(DV.w + bias); \
        EB##_u0 = dt0 * XV.x; EB##_u1 = dt1 * XV.y; \
        EB##_u2 = dt2 * XV.z; EB##_u3 = dt3 * XV.w; \
        EB##_e0 = exp2v8(splat8(dt0) * A2v); \
        EB##_e1 = exp2v8(splat8(dt1) * A2v); \
        EB##_e2 = exp2v8(splat8(dt2) * A2v); \
        EB##_e3 = exp2v8(splat8(dt3) * A2v); \
    }

    MAKE_E(E0, P0_dv, P0_xv)   // chunk 0's trans block (only place it's exposed)

// Fused-DPP scan steps (round 8, proven).  bound_ctrl deliberately omitted:
// invalid lanes keep dest (scan identity).
#define SCAN_ASM_STEP(SHR) \
    { \
        _Pragma("unroll") \
        for (int i = 0; i < NH; ++i) { \
            asm("v_fmac_f32_dpp %0, %0, %1 row_shr:" #SHR " row_mask:0xf bank_mask:0xf" \
                : "+v"(S3v[i]) : "v"(F3v[i])); \
            asm("v_mul_f32_dpp %0, %0, %0 row_shr:" #SHR " row_mask:0xf bank_mask:0xf" \
                : "+v"(F3v[i])); \
        } \
    }
#define SCAN_ASM_BCAST15 \
    { \
        _Pragma("unroll") \
        for (int i = 0; i < NH; ++i) { \
            asm("v_fmac_f32_dpp %0, %0, %1 row_bcast:15 row_mask:0xa bank_mask:0xf" \
                : "+v"(S3v[i]) : "v"(F3v[i])); \
            asm("v_mul_f32_dpp %0, %0, %0 row_bcast:15 row_mask:0xa bank_mask:0xf" \
                : "+v"(F3v[i])); \
        } \
    }

#define BODY(c, CUR, NXT, EC, EN) { \
    const int off  = (c) * LC + s * 4; \
    /* clamp: last chunk re-prefetches ITS OWN data (L1-hot) instead of wrapping */ \
    const int offn = (((c) == NCHUNK - 1) ? (c) : (c) + 1) * LC + s * 4; \
    /* ---- next-chunk early-use prefetch FIRST ---- */ \
    NXT##_dv = *(const f4*)(delta + chbase + offn); \
    NXT##_xv = *(const f4*)(x     + chbase + offn); \
    NXT##_B0 = *(const f4*)(Bp + 0 * L_ + offn); \
    NXT##_B1 = *(const f4*)(Bp + 1 * L_ + offn); \
    NXT##_B2 = *(const f4*)(Bp + 2 * L_ + offn); \
    NXT##_B3 = *(const f4*)(Bp + 3 * L_ + offn); \
    NXT##_B4 = *(const f4*)(Bp + 4 * L_ + offn); \
    NXT##_B5 = *(const f4*)(Bp + 5 * L_ + offn); \
    NXT##_B6 = *(const f4*)(Bp + 6 * L_ + offn); \
    NXT##_B7 = *(const f4*)(Bp + 7 * L_ + offn); \
    /* ---- current-chunk late-use loads (L2-hot, scan+pass1 of cover) ---- */ \
    f4 zv  = *(const f4*)(z + chbase + off); \
    f4 Cv0 = *(const f4*)(Cp + 0 * L_ + off); \
    f4 Cv1 = *(const f4*)(Cp + 1 * L_ + off); \
    f4 Cv2 = *(const f4*)(Cp + 2 * L_ + off); \
    f4 Cv3 = *(const f4*)(Cp + 3 * L_ + off); \
    f4 Cv4 = *(const f4*)(Cp + 4 * L_ + off); \
    f4 Cv5 = *(const f4*)(Cp + 5 * L_ + off); \
    f4 Cv6 = *(const f4*)(Cp + 6 * L_ + off); \
    f4 Cv7 = *(const f4*)(Cp + 7 * L_ + off); \
    /* ---- transpose B/C fragments to per-j state-vectors ---- */ \
    f8 tB0 = {CUR##_B0.x,CUR##_B1.x,CUR##_B2.x,CUR##_B3.x,CUR##_B4.x,CUR##_B5.x,CUR##_B6.x,CUR##_B7.x}; \
    f8 tB1 = {CUR##_B0.y,CUR##_B1.y,CUR##_B2.y,CUR##_B3.y,CUR##_B4.y,CUR##_B5.y,CUR##_B6.y,CUR##_B7.y}; \
    f8 tB2 = {CUR##_B0.z,CUR##_B1.z,CUR##_B2.z,CUR##_B3.z,CUR##_B4.z,CUR##_B5.z,CUR##_B6.z,CUR##_B7.z}; \
    f8 tB3 = {CUR##_B0.w,CUR##_B1.w,CUR##_B2.w,CUR##_B3.w,CUR##_B4.w,CUR##_B5.w,CUR##_B6.w,CUR##_B7.w}; \
    f8 SC0 = {Cv0.x,Cv1.x,Cv2.x,Cv3.x,Cv4.x,Cv5.x,Cv6.x,Cv7.x}; \
    f8 SC1 = {Cv0.y,Cv1.y,Cv2.y,Cv3.y,Cv4.y,Cv5.y,Cv6.y,Cv7.y}; \
    f8 SC2 = {Cv0.z,Cv1.z,Cv2.z,Cv3.z,Cv4.z,Cv5.z,Cv6.z,Cv7.z}; \
    f8 SC3 = {Cv0.w,Cv1.w,Cv2.w,Cv3.w,Cv4.w,Cv5.w,Cv6.w,Cv7.w}; \
    /* ---- pass 1 from the PIPELINED e/u (computed last body) ---- */ \
    f8 S0v = splat8(EC##_u0) * tB0;                    f8 F0v = EC##_e0; \
    f8 S1v = EC##_e1 * S0v + splat8(EC##_u1) * tB1;    f8 F1v = EC##_e1 * F0v; \
    f8 S2v = EC##_e2 * S1v + splat8(EC##_u2) * tB2;    f8 F2v = EC##_e2 * F1v; \
    f8 S3v = EC##_e3 * S2v + splat8(EC##_u3) * tB3;    f8 F3v = EC##_e3 * F2v; \
    /* ---- width-32 inclusive scan of (F3v,S3v): fused DPP asm ---- */ \
    SCAN_ASM_STEP(1) \
    SCAN_ASM_STEP(2) \
    SCAN_ASM_STEP(4) \
    SCAN_ASM_STEP(8) \
    SCAN_ASM_BCAST15   /* rows 1,3 only; rows 0,2 not written (mask 0xA) */ \
    /* ---- PIPELINED trans for chunk c+1: issued here, consumed next body. \
       fold/pass2/epilogue below are independent -> wave keeps issuing while \
       the trans pipe drains in the background ---- */ \
    MAKE_E(EN, NXT##_dv, NXT##_xv) \
    /* ---- fold chunk carry; h_in entering this lane's segment ---- */ \
    f8 h; f8 hincv; \
    _Pragma("unroll") \
    for (int i = 0; i < NH; ++i) { \
        hincv[i] = fmaf(carry[i], F3v[i], S3v[i]);          /* state after elem 3 */ \
        float hup = dpp0<DPP_WAVE_SHR1, 0xF>(hincv[i]);     /* lane n <- n-1 */ \
        h[i] = (s == 0) ? carry[i] : hup; \
        carry[i] = __shfl(hincv[i], 31, 32);                /* broadcast within half */ \
    } \
    /* ---- pass 2: independent per-element states; y_j = <h_j, C_j> ---- */ \
    f8 t0 = F0v * h + S0v;  float y0 = dot8(t0, SC0); \
    f8 t1 = F1v * h + S1v;  float y1 = dot8(t1, SC1); \
    f8 t2 = F2v * h + S2v;  float y2 = dot8(t2, SC2); \
    float y3 = dot8(hincv, SC3); \
    /* ---- combine the two state-halves; epilogue; half-wave store ---- */ \
    y0 += __shfl_xor(y0, 32, 64); \
    y1 += __shfl_xor(y1, 32, 64); \
    y2 += __shfl_xor(y2, 32, 64); \
    y3 += __shfl_xor(y3, 32, 64); \
    if (g == 0) { \
        float s0 = rcpf_(1.0f + exp2f_(-zv.x * LOG2E)); \
        float s1 = rcpf_(1.0f + exp2f_(-zv.y * LOG2E)); \
        float s2 = rcpf_(1.0f + exp2f_(-zv.z * LOG2E)); \
        float s3 = rcpf_(1.0f + exp2f_(-zv.w * LOG2E)); \
        f4 ov = { (y0 + CUR##_xv.x * Dd) * (zv.x * s0), \
                  (y1 + CUR##_xv.y * Dd) * (zv.y * s1), \
                  (y2 + CUR##_xv.z * Dd) * (zv.z * s2), \
                  (y3 + CUR##_xv.w * Dd) * (zv.w * s3) }; \
        *(f4*)(out + chbase + off) = ov; \
    } \
}

    for (int cc = 0; cc < NCHUNK; cc += 2) {
        BODY(cc,     P0, P1, E0, E1)
        BODY(cc + 1, P1, P0, E1, E0)
    }
}

extern "C" void kernel_launch(void* const* d_in, const int* in_sizes, int n_in,
                              void* d_out, int out_size, void* d_ws, size_t ws_size,
                              hipStream_t stream) {
    const float* x     = (const float*)d_in[0];
    const float* delta = (const float*)d_in[1];
    const float* A     = (const float*)d_in[2];
    const float* Bm    = (const float*)d_in[3];
    const float* Cm    = (const float*)d_in[4];
    const float* Dv    = (const float*)d_in[5];
    const float* z     = (const float*)d_in[6];
    const float* dbias = (const float*)d_in[7];
    float* out = (float*)d_out;

    dim3 grid(NCH);    // 3072 blocks = 1 wave = 1 channel each
    dim3 block(64);
    ssm_scan_kernel<<<grid, block, 0, stream>>>(x, delta, A, Bm, Cm, Dv, z, dbias, out);
}